// Round 1
// baseline (152.534 us; speedup 1.0000x reference)
//
#include <hip/hip_runtime.h>
#include <hip/hip_bf16.h>
#include <stdint.h>

#define NROWS 8192
#define DIM   512

typedef short bf16x8 __attribute__((ext_vector_type(8)));
typedef float f32x4  __attribute__((ext_vector_type(4)));

// ---- order-preserving float<->uint encoding for atomicMax on floats ----
__device__ __forceinline__ unsigned fenc(float f) {
  unsigned u = __float_as_uint(f);
  return (u & 0x80000000u) ? ~u : (u | 0x80000000u);
}
__device__ __forceinline__ float fdec(unsigned u) {
  unsigned b = (u & 0x80000000u) ? (u ^ 0x80000000u) : ~u;
  return __uint_as_float(b);
}

// RNE f32 -> bf16 (no NaN inputs here)
__device__ __forceinline__ unsigned short f2bf(float x) {
  unsigned u = __float_as_uint(x);
  u += 0x7FFFu + ((u >> 16) & 1u);
  return (unsigned short)(u >> 16);
}

__device__ __forceinline__ void async16(const void* g, void* l) {
  __builtin_amdgcn_global_load_lds(
      (const __attribute__((address_space(1))) unsigned int*)g,
      (__attribute__((address_space(3))) unsigned int*)l, 16, 0, 0);
}

// ---- init the encoded max arrays (2 * 8192 entries) to enc(-2.0f) ----
__global__ void init_max_kernel(unsigned* __restrict__ enc) {
  int i = blockIdx.x * blockDim.x + threadIdx.x;
  if (i < 2 * NROWS) enc[i] = fenc(-2.0f);
}

// ---- normalize one row (512 f32) -> bf16, one block (128 thr) per row ----
__global__ __launch_bounds__(128) void normalize_kernel(
    const float* __restrict__ src, unsigned short* __restrict__ dst) {
  const int row = blockIdx.x;
  const int t = threadIdx.x;
  const float4* p = (const float4*)(src + (size_t)row * DIM);
  float4 v = p[t];
  float ss = v.x * v.x + v.y * v.y + v.z * v.z + v.w * v.w;
#pragma unroll
  for (int m = 1; m <= 32; m <<= 1) ss += __shfl_xor(ss, m);
  __shared__ float sred[2];
  if ((t & 63) == 0) sred[t >> 6] = ss;
  __syncthreads();
  const float tot = sred[0] + sred[1];
  const float sc = 1.0f / fmaxf(sqrtf(tot), 1e-8f);
  ushort4 o;
  o.x = f2bf(v.x * sc);
  o.y = f2bf(v.y * sc);
  o.z = f2bf(v.z * sc);
  o.w = f2bf(v.w * sc);
  ((ushort4*)(dst + (size_t)row * DIM))[t] = o;
}

// ---- bf16 MFMA GEMM (C = Xn * Yn^T), 128x128 tile, fused row/col max ----
__global__ __launch_bounds__(256) void gemm_max_kernel(
    const unsigned short* __restrict__ Xn, const unsigned short* __restrict__ Yn,
    unsigned* __restrict__ rowmax, unsigned* __restrict__ colmax) {
  __shared__ unsigned short As[128 * 64];  // 16 KB
  __shared__ unsigned short Bs[128 * 64];  // 16 KB

  const int t = threadIdx.x;
  const int lane = t & 63;
  const int wave = t >> 6;
  const int wr = wave >> 1;  // 2x2 wave grid, each wave -> 64x64 output
  const int wc = wave & 1;

  const int bid = blockIdx.x;
  const int brow = (bid & 63) * 128;
  const int bcol = (bid >> 6) * 128;

  f32x4 acc[4][4];
#pragma unroll
  for (int m = 0; m < 4; ++m)
#pragma unroll
    for (int n = 0; n < 4; ++n) acc[m][n] = (f32x4){0.f, 0.f, 0.f, 0.f};

  // staging addressing: thread t stages 16B; row = t/8, col = (t%8)*8 elems
  const int rr = t >> 3;
  const int cc = (t & 7) * 8;
  const unsigned short* Ag = Xn + (size_t)(brow + rr) * DIM + cc;
  const unsigned short* Bg = Yn + (size_t)(bcol + rr) * DIM + cc;
  unsigned short* Al = As + rr * 64 + cc;  // == As + t*8 (lane-linear: OK for global_load_lds)
  unsigned short* Bl = Bs + rr * 64 + cc;

  const int frow = lane & 15;        // fragment row/col within 16
  const int ko_base = (lane >> 4) * 8;

  for (int k0 = 0; k0 < DIM; k0 += 64) {
    __syncthreads();  // previous compute done -> safe to overwrite LDS
#pragma unroll
    for (int i = 0; i < 4; ++i) {
      async16(Ag + (size_t)(i * 32) * DIM + k0, Al + i * 32 * 64);
      async16(Bg + (size_t)(i * 32) * DIM + k0, Bl + i * 32 * 64);
    }
    __syncthreads();  // compiler drains vmcnt(0) before barrier -> LDS ready
#pragma unroll
    for (int kk = 0; kk < 2; ++kk) {
      bf16x8 a[4], b[4];
      const int ko = kk * 32 + ko_base;
#pragma unroll
      for (int m = 0; m < 4; ++m)
        a[m] = *(const bf16x8*)(As + (wr * 64 + m * 16 + frow) * 64 + ko);
#pragma unroll
      for (int n = 0; n < 4; ++n)
        b[n] = *(const bf16x8*)(Bs + (wc * 64 + n * 16 + frow) * 64 + ko);
#pragma unroll
      for (int m = 0; m < 4; ++m)
#pragma unroll
        for (int n = 0; n < 4; ++n)
          acc[m][n] = __builtin_amdgcn_mfma_f32_16x16x32_bf16(a[m], b[n], acc[m][n], 0, 0, 0);
    }
  }

  // ---- epilogue: C/D layout col=lane&15, row=(lane>>4)*4+reg ----
  // row maxes: reduce over n and over lanes sharing (lane>>4)
#pragma unroll
  for (int m = 0; m < 4; ++m) {
    f32x4 rm = acc[m][0];
#pragma unroll
    for (int n = 1; n < 4; ++n) {
      rm.x = fmaxf(rm.x, acc[m][n].x);
      rm.y = fmaxf(rm.y, acc[m][n].y);
      rm.z = fmaxf(rm.z, acc[m][n].z);
      rm.w = fmaxf(rm.w, acc[m][n].w);
    }
#pragma unroll
    for (int r = 0; r < 4; ++r) {
      float v = (r == 0) ? rm.x : (r == 1) ? rm.y : (r == 2) ? rm.z : rm.w;
      v = fmaxf(v, __shfl_xor(v, 1));
      v = fmaxf(v, __shfl_xor(v, 2));
      v = fmaxf(v, __shfl_xor(v, 4));
      v = fmaxf(v, __shfl_xor(v, 8));
      if ((lane & 15) == 0) {
        const int grow = brow + wr * 64 + m * 16 + (lane >> 4) * 4 + r;
        atomicMax(rowmax + grow, fenc(v));
      }
    }
  }
  // col maxes: reduce over m,reg and over the four (lane>>4) groups
#pragma unroll
  for (int n = 0; n < 4; ++n) {
    float cm = -2.0f;
#pragma unroll
    for (int m = 0; m < 4; ++m) {
      cm = fmaxf(cm, acc[m][n].x);
      cm = fmaxf(cm, acc[m][n].y);
      cm = fmaxf(cm, acc[m][n].z);
      cm = fmaxf(cm, acc[m][n].w);
    }
    cm = fmaxf(cm, __shfl_xor(cm, 16));
    cm = fmaxf(cm, __shfl_xor(cm, 32));
    if (lane < 16) {
      const int gcol = bcol + wc * 64 + n * 16 + lane;
      atomicMax(colmax + gcol, fenc(cm));
    }
  }
}

// ---- entropy: out[b] = -sum( exp(lp)*lp ), lp = -0.5*z^2 + 0.285034... ----
__global__ __launch_bounds__(256) void entropy_kernel(
    const unsigned* __restrict__ enc, float* __restrict__ out) {
  const int which = blockIdx.x;  // 0 = rowmax, 1 = colmax
  const unsigned* e = enc + which * NROWS;
  float s = 0.0f;
  for (int i = threadIdx.x; i < NROWS; i += 256) {
    const float x = fdec(e[i]);
    const float z = (x - 1.0f) * (1.0f / 0.3f);
    const float lp = -0.5f * z * z + 0.2850342711439819f;  // -log(0.3)-0.5*log(2*pi)
    s += expf(lp) * lp;
  }
#pragma unroll
  for (int m = 1; m <= 32; m <<= 1) s += __shfl_xor(s, m);
  __shared__ float sr[4];
  if ((threadIdx.x & 63) == 0) sr[threadIdx.x >> 6] = s;
  __syncthreads();
  if (threadIdx.x == 0) out[which] = -(sr[0] + sr[1] + sr[2] + sr[3]);
}

extern "C" void kernel_launch(void* const* d_in, const int* in_sizes, int n_in,
                              void* d_out, int out_size, void* d_ws, size_t ws_size,
                              hipStream_t stream) {
  const float* ex = (const float*)d_in[0];
  const float* ey = (const float*)d_in[1];

  unsigned short* Xn = (unsigned short*)d_ws;                 // 8 MB
  unsigned short* Yn = Xn + (size_t)NROWS * DIM;              // 8 MB
  unsigned* enc = (unsigned*)(Yn + (size_t)NROWS * DIM);      // 2*8192 u32
  float* out = (float*)d_out;

  hipLaunchKernelGGL(init_max_kernel, dim3(64), dim3(256), 0, stream, enc);
  hipLaunchKernelGGL(normalize_kernel, dim3(NROWS), dim3(128), 0, stream, ex, Xn);
  hipLaunchKernelGGL(normalize_kernel, dim3(NROWS), dim3(128), 0, stream, ey, Yn);
  hipLaunchKernelGGL(gemm_max_kernel, dim3(64 * 64), dim3(256), 0, stream,
                     Xn, Yn, enc, enc + NROWS);
  hipLaunchKernelGGL(entropy_kernel, dim3(2), dim3(256), 0, stream, enc, out);
}